// Round 1
// baseline (9643.703 us; speedup 1.0000x reference)
//
#include <hip/hip_runtime.h>
#include <stdint.h>

constexpr int kV = 128, kE = 100, kH = 1024, kB = 64, kT = 512, kH3 = 3072;

typedef __bf16 bf16_t;
typedef __bf16 bf16x8 __attribute__((ext_vector_type(8)));
typedef float f32x4 __attribute__((ext_vector_type(4)));

// ---------------- P = emb @ Wx + b_in (+ b_rec for z,r gates) : [128][3072] f32
__global__ void k_prep_P(const float* __restrict__ emb, const float* __restrict__ Wx,
                         const float* __restrict__ b_in, const float* __restrict__ b_rec,
                         float* __restrict__ P) {
    const int n = blockIdx.x * 256 + threadIdx.x;   // 12 blocks.x * 256 = 3072
    const int v0 = blockIdx.y * 32;                 // 4 blocks.y
    float wcol[kE];
#pragma unroll
    for (int e = 0; e < kE; ++e) wcol[e] = Wx[e * kH3 + n];
    const float bias = b_in[n] + (n < 2 * kH ? b_rec[n] : 0.f);
    for (int vi = 0; vi < 32; ++vi) {
        const int v = v0 + vi;
        float acc = bias;
#pragma unroll
        for (int e = 0; e < kE; ++e) acc += emb[v * kE + e] * wcol[e];
        P[v * kH3 + n] = acc;
    }
}

// ---------------- WdT = bf16(Wd^T) : [128][1024]
__global__ void k_prep_WdT(const float* __restrict__ Wd, bf16_t* __restrict__ WdT) {
    const int i = blockIdx.x * 256 + threadIdx.x;   // 512 blocks -> 131072
    const int v = i & 127, k = i >> 7;
    WdT[v * kH + k] = (bf16_t)Wd[k * kV + v];
}

// ---------------- persistent GRU scan: 128 WGs x 256 thr, WG w owns H-cols [8w,8w+8)
__launch_bounds__(256, 1)
__global__ void k_scan(const int* __restrict__ tokens, const float* __restrict__ Uh,
                       const float* __restrict__ Pg, const float* __restrict__ b_rec,
                       bf16_t* __restrict__ hbuf, bf16_t* __restrict__ seq,
                       unsigned* __restrict__ bar) {
    // 40 rows (32 used) to push LDS > 80KB -> exactly 1 WG/CU -> 128 CUs busy
    __shared__ __align__(16) bf16_t UhT[40][1032];
    __shared__ float Pl[kV][24];
    const int w = blockIdx.x;
    const int tid = threadIdx.x;
    const int lane = tid & 63, wave = tid >> 6;
    const int r16 = lane & 15, grp = lane >> 4;

    // zero the 32 used UhT rows (cols 24..31 stay zero = N-pad)
    for (int i = tid; i < 32 * 1032; i += 256) ((bf16_t*)UhT)[i] = (bf16_t)0.f;
    __syncthreads();
    // stage Uh slice, transposed, bf16:  UhT[n][k] = Uh[k][col(n)]
    for (int idx = tid; idx < 24 * 1024; idx += 256) {
        const int n = idx % 24, k = idx / 24;
        const int c = (n < 8) ? (8 * w + n) : (n < 16) ? (kH + 8 * w + n - 8) : (2 * kH + 8 * w + n - 16);
        UhT[n][k] = (bf16_t)Uh[k * kH3 + c];
    }
    // stage P gather table for this WG's 24 columns
    for (int idx = tid; idx < kV * 24; idx += 256) {
        const int v = idx / 24, n = idx % 24;
        const int c = (n < 8) ? (8 * w + n) : (n < 16) ? (kH + 8 * w + n - 8) : (2 * kH + 8 * w + n - 16);
        Pl[v][n] = Pg[v * kH3 + c];
    }
    __syncthreads();

    const bool act = (r16 < 8);
    const int jj = r16;
    const int jcol = 8 * w + jj;
    float brh = act ? b_rec[2 * kH + jcol] : 0.f;   // b_rec for hh gate (NOT foldable: scaled by r)
    float hreg[4] = {0.f, 0.f, 0.f, 0.f};           // this lane's h[b][jcol] state, f32

    for (int t = 0; t < kT; ++t) {
        const int cur = t & 1;
        const bf16_t* __restrict__ hprev = hbuf + (cur ^ 1) * (kB * kH);
        bf16_t* __restrict__ hnext = hbuf + cur * (kB * kH);

        f32x4 acc0 = {0.f, 0.f, 0.f, 0.f};   // N-tile 0: cols n=0..15  (z: n<8, r: n in 8..15)
        f32x4 acc1 = {0.f, 0.f, 0.f, 0.f};   // N-tile 1: cols n=16..31 (hh: n in 16..23)
        if (t > 0) {
            // A-frags (h rows) straight from global, agent-coherent (cross-XCD fresh)
            const bf16_t* aptr = hprev + (16 * wave + r16) * kH + 8 * grp;
#pragma unroll 4
            for (int ks = 0; ks < 32; ++ks) {
                const int k0 = 32 * ks;
                unsigned long long alo = __hip_atomic_load((unsigned long long*)(aptr + k0),
                                                           __ATOMIC_RELAXED, __HIP_MEMORY_SCOPE_AGENT);
                unsigned long long ahi = __hip_atomic_load((unsigned long long*)(aptr + k0 + 4),
                                                           __ATOMIC_RELAXED, __HIP_MEMORY_SCOPE_AGENT);
                union { unsigned long long u[2]; bf16x8 v; } au;
                au.u[0] = alo; au.u[1] = ahi;
                const int kk = k0 + 8 * grp;
                bf16x8 b0 = *(const bf16x8*)&UhT[r16][kk];
                bf16x8 b1 = *(const bf16x8*)&UhT[16 + r16][kk];
                acc0 = __builtin_amdgcn_mfma_f32_16x16x32_bf16(au.v, b0, acc0, 0, 0, 0);
                acc1 = __builtin_amdgcn_mfma_f32_16x16x32_bf16(au.v, b1, acc1, 0, 0, 0);
            }
        }

        // bring r-gate pre-activations (cols 8..15) to the z-lanes (cols 0..7)
        float racc[4];
#pragma unroll
        for (int q = 0; q < 4; ++q) racc[q] = __shfl_xor(acc0[q], 8, 64);

        if (act) {
#pragma unroll
            for (int q = 0; q < 4; ++q) {
                const int b = 16 * wave + 4 * grp + q;
                const int tok = tokens[b * kT + t];
                const float xz = Pl[tok][jj];
                const float xr = Pl[tok][8 + jj];
                const float xh = Pl[tok][16 + jj];
                const float z = 1.f / (1.f + __expf(-(xz + acc0[q])));
                const float r = 1.f / (1.f + __expf(-(xr + racc[q])));
                float hh = xh + r * (acc1[q] + brh);
                hh = hh > 0.f ? hh : 0.f;
                const float hnew = z * hreg[q] + (1.f - z) * hh;
                hreg[q] = hnew;
                union { bf16_t h; unsigned short u; } cv; cv.h = (bf16_t)hnew;
                __hip_atomic_store((unsigned short*)(hnext + b * kH + jcol), cv.u,
                                   __ATOMIC_RELAXED, __HIP_MEMORY_SCOPE_AGENT);
                seq[(b * kT + t) * kH + jcol] = cv.h;
            }
        }

        if (t < kT - 1) {
            __syncthreads();   // drains vmcnt: all agent stores complete before arrival
            if (tid == 0) {
                unsigned g = __hip_atomic_load(&bar[1], __ATOMIC_RELAXED, __HIP_MEMORY_SCOPE_AGENT);
                unsigned old = __hip_atomic_fetch_add(&bar[0], 1u, __ATOMIC_ACQ_REL, __HIP_MEMORY_SCOPE_AGENT);
                if (old == 127u) {
                    __hip_atomic_store(&bar[0], 0u, __ATOMIC_RELAXED, __HIP_MEMORY_SCOPE_AGENT);
                    __hip_atomic_fetch_add(&bar[1], 1u, __ATOMIC_RELEASE, __HIP_MEMORY_SCOPE_AGENT);
                } else {
                    long guard = 0;
                    while (__hip_atomic_load(&bar[1], __ATOMIC_ACQUIRE, __HIP_MEMORY_SCOPE_AGENT) == g) {
                        __builtin_amdgcn_s_sleep(1);
                        if (++guard > (1L << 26)) break;   // anti-deadlock escape
                    }
                }
            }
            __syncthreads();
        }
    }
}

// ---------------- logits = seq @ Wd^T' + bd : 256 WGs x 128 rows
__launch_bounds__(256, 1)
__global__ void k_logits(const bf16_t* __restrict__ seq, const bf16_t* __restrict__ WdT,
                         const float* __restrict__ bd, float* __restrict__ out) {
    const int m0 = blockIdx.x * 128;
    const int lane = threadIdx.x & 63, wave = threadIdx.x >> 6;
    const int r16 = lane & 15, grp = lane >> 4;
    f32x4 acc[2][8];
#pragma unroll
    for (int i = 0; i < 2; ++i)
#pragma unroll
        for (int n = 0; n < 8; ++n) acc[i][n] = (f32x4){0.f, 0.f, 0.f, 0.f};
    const bf16_t* a0p = seq + (m0 + 32 * wave + r16) * kH + 8 * grp;
    const bf16_t* a1p = a0p + 16 * kH;
    const bf16_t* bp = WdT + r16 * kH + 8 * grp;
    for (int ks = 0; ks < 32; ++ks) {
        const int k0 = 32 * ks;
        bf16x8 a0 = *(const bf16x8*)(a0p + k0);
        bf16x8 a1 = *(const bf16x8*)(a1p + k0);
#pragma unroll
        for (int nt = 0; nt < 8; ++nt) {
            bf16x8 b = *(const bf16x8*)(bp + nt * 16 * kH + k0);
            acc[0][nt] = __builtin_amdgcn_mfma_f32_16x16x32_bf16(a0, b, acc[0][nt], 0, 0, 0);
            acc[1][nt] = __builtin_amdgcn_mfma_f32_16x16x32_bf16(a1, b, acc[1][nt], 0, 0, 0);
        }
    }
#pragma unroll
    for (int i = 0; i < 2; ++i)
#pragma unroll
        for (int nt = 0; nt < 8; ++nt) {
            const int v = 16 * nt + r16;
            const float bias = bd[v];
#pragma unroll
            for (int q = 0; q < 4; ++q) {
                const int m = m0 + 32 * wave + 16 * i + 4 * grp + q;
                out[m * kV + v] = acc[i][nt][q] + bias;
            }
        }
}

extern "C" void kernel_launch(void* const* d_in, const int* in_sizes, int n_in,
                              void* d_out, int out_size, void* d_ws, size_t ws_size,
                              hipStream_t stream) {
    const int*   tokens = (const int*)d_in[0];
    const float* emb    = (const float*)d_in[1];
    const float* Wx     = (const float*)d_in[2];
    const float* Uh     = (const float*)d_in[3];
    const float* b_in   = (const float*)d_in[4];
    const float* b_rec  = (const float*)d_in[5];
    const float* Wd     = (const float*)d_in[6];
    const float* bd     = (const float*)d_in[7];
    float* out = (float*)d_out;

    char* ws = (char*)d_ws;
    bf16_t*   seq  = (bf16_t*)ws;                    // 64*512*1024*2 = 67,108,864 B
    float*    P    = (float*)(ws + 67108864);        // 128*3072*4   =  1,572,864 B
    bf16_t*   WdT  = (bf16_t*)(ws + 68681728);       // 128*1024*2   =    262,144 B
    bf16_t*   hbuf = (bf16_t*)(ws + 68943872);       // 2*64*1024*2  =    262,144 B
    unsigned* bar  = (unsigned*)(ws + 69206016);     // 8 B

    k_prep_P<<<dim3(12, 4), 256, 0, stream>>>(emb, Wx, b_in, b_rec, P);
    k_prep_WdT<<<512, 256, 0, stream>>>(Wd, WdT);
    hipMemsetAsync(bar, 0, 8, stream);
    k_scan<<<128, 256, 0, stream>>>(tokens, Uh, P, b_rec, hbuf, seq, bar);
    k_logits<<<256, 256, 0, stream>>>(seq, WdT, bd, out);
}

// Round 2
// 9627.827 us; speedup vs baseline: 1.0016x; 1.0016x over previous
//
#include <hip/hip_runtime.h>
#include <stdint.h>

constexpr int kV = 128, kE = 100, kH = 1024, kB = 64, kT = 512, kH3 = 3072;

typedef __bf16 bf16_t;
typedef __bf16 bf16x8 __attribute__((ext_vector_type(8)));
typedef float f32x4 __attribute__((ext_vector_type(4)));

// ---------------- P = emb @ Wx + b_in (+ b_rec for z,r gates) : [128][3072] f32
__global__ void k_prep_P(const float* __restrict__ emb, const float* __restrict__ Wx,
                         const float* __restrict__ b_in, const float* __restrict__ b_rec,
                         float* __restrict__ P) {
    const int n = blockIdx.x * 256 + threadIdx.x;   // 12 blocks.x * 256 = 3072
    const int v0 = blockIdx.y * 32;                 // 4 blocks.y
    float wcol[kE];
#pragma unroll
    for (int e = 0; e < kE; ++e) wcol[e] = Wx[e * kH3 + n];
    const float bias = b_in[n] + (n < 2 * kH ? b_rec[n] : 0.f);
    for (int vi = 0; vi < 32; ++vi) {
        const int v = v0 + vi;
        float acc = bias;
#pragma unroll
        for (int e = 0; e < kE; ++e) acc += emb[v * kE + e] * wcol[e];
        P[v * kH3 + n] = acc;
    }
}

// ---------------- WdT = bf16(Wd^T) : [128][1024]
__global__ void k_prep_WdT(const float* __restrict__ Wd, bf16_t* __restrict__ WdT) {
    const int i = blockIdx.x * 256 + threadIdx.x;   // 512 blocks -> 131072
    const int v = i & 127, k = i >> 7;
    WdT[v * kH + k] = (bf16_t)Wd[k * kV + v];
}

// ---------------- persistent GRU scan: 128 WGs x 256 thr, WG w owns H-cols [8w,8w+8)
__launch_bounds__(256, 1)
__global__ void k_scan(const int* __restrict__ tokens, const float* __restrict__ Uh,
                       const float* __restrict__ Pg, const float* __restrict__ b_rec,
                       bf16_t* __restrict__ hbuf, bf16_t* __restrict__ seq,
                       unsigned* __restrict__ arrive) {
    // 40 rows (32 used) to push LDS > 80KB -> exactly 1 WG/CU -> 128 CUs busy
    __shared__ __align__(16) bf16_t UhT[40][1032];
    __shared__ float Pl[kV][24];
    const int w = blockIdx.x;
    const int tid = threadIdx.x;
    const int lane = tid & 63, wave = tid >> 6;
    const int r16 = lane & 15, grp = lane >> 4;

    // zero the 32 used UhT rows (cols 24..31 stay zero = N-pad)
    for (int i = tid; i < 32 * 1032; i += 256) ((bf16_t*)UhT)[i] = (bf16_t)0.f;
    __syncthreads();
    // stage Uh slice, transposed, bf16:  UhT[n][k] = Uh[k][col(n)]
    for (int idx = tid; idx < 24 * 1024; idx += 256) {
        const int n = idx % 24, k = idx / 24;
        const int c = (n < 8) ? (8 * w + n) : (n < 16) ? (kH + 8 * w + n - 8) : (2 * kH + 8 * w + n - 16);
        UhT[n][k] = (bf16_t)Uh[k * kH3 + c];
    }
    // stage P gather table for this WG's 24 columns
    for (int idx = tid; idx < kV * 24; idx += 256) {
        const int v = idx / 24, n = idx % 24;
        const int c = (n < 8) ? (8 * w + n) : (n < 16) ? (kH + 8 * w + n - 8) : (2 * kH + 8 * w + n - 16);
        Pl[v][n] = Pg[v * kH3 + c];
    }
    __syncthreads();

    const bool act = (r16 < 8);
    const int jj = r16;
    const int jcol = 8 * w + jj;
    float brh = act ? b_rec[2 * kH + jcol] : 0.f;   // b_rec for hh gate (NOT foldable: scaled by r)
    float hreg[4] = {0.f, 0.f, 0.f, 0.f};           // this lane's h[b][jcol] state, f32

    for (int t = 0; t < kT; ++t) {
        const int cur = t & 1;
        const bf16_t* __restrict__ hprev = hbuf + (cur ^ 1) * (kB * kH);
        bf16_t* __restrict__ hnext = hbuf + cur * (kB * kH);

        f32x4 acc0 = {0.f, 0.f, 0.f, 0.f};   // N-tile 0: cols n=0..15  (z: n<8, r: n in 8..15)
        f32x4 acc1 = {0.f, 0.f, 0.f, 0.f};   // N-tile 1: cols n=16..31 (hh: n in 16..23)
        if (t > 0) {
            // A-frags (h rows) straight from global, agent-coherent (cross-XCD fresh)
            const bf16_t* aptr = hprev + (16 * wave + r16) * kH + 8 * grp;
#pragma unroll 4
            for (int ks = 0; ks < 32; ++ks) {
                const int k0 = 32 * ks;
                unsigned long long alo = __hip_atomic_load((unsigned long long*)(aptr + k0),
                                                           __ATOMIC_RELAXED, __HIP_MEMORY_SCOPE_AGENT);
                unsigned long long ahi = __hip_atomic_load((unsigned long long*)(aptr + k0 + 4),
                                                           __ATOMIC_RELAXED, __HIP_MEMORY_SCOPE_AGENT);
                union { unsigned long long u[2]; bf16x8 v; } au;
                au.u[0] = alo; au.u[1] = ahi;
                const int kk = k0 + 8 * grp;
                bf16x8 b0 = *(const bf16x8*)&UhT[r16][kk];
                bf16x8 b1 = *(const bf16x8*)&UhT[16 + r16][kk];
                acc0 = __builtin_amdgcn_mfma_f32_16x16x32_bf16(au.v, b0, acc0, 0, 0, 0);
                acc1 = __builtin_amdgcn_mfma_f32_16x16x32_bf16(au.v, b1, acc1, 0, 0, 0);
            }
        }

        // bring r-gate pre-activations (cols 8..15) to the z-lanes (cols 0..7)
        float racc[4];
#pragma unroll
        for (int q = 0; q < 4; ++q) racc[q] = __shfl_xor(acc0[q], 8, 64);

        if (act) {
#pragma unroll
            for (int q = 0; q < 4; ++q) {
                const int b = 16 * wave + 4 * grp + q;
                const int tok = tokens[b * kT + t];
                const float xz = Pl[tok][jj];
                const float xr = Pl[tok][8 + jj];
                const float xh = Pl[tok][16 + jj];
                const float z = 1.f / (1.f + __expf(-(xz + acc0[q])));
                const float r = 1.f / (1.f + __expf(-(xr + racc[q])));
                float hh = xh + r * (acc1[q] + brh);
                hh = hh > 0.f ? hh : 0.f;
                const float hnew = z * hreg[q] + (1.f - z) * hh;
                hreg[q] = hnew;
                union { bf16_t h; unsigned short u; } cv; cv.h = (bf16_t)hnew;
                __hip_atomic_store((unsigned short*)(hnext + b * kH + jcol), cv.u,
                                   __ATOMIC_RELAXED, __HIP_MEMORY_SCOPE_AGENT);
                seq[(b * kT + t) * kH + jcol] = cv.h;
            }
        }

        if (t < kT - 1) {
            // flag-array barrier: no RMW contention. __syncthreads drains vmcnt(0)
            // for ALL waves of this WG before tid 0 publishes the arrival flag.
            __syncthreads();
            if (tid == 0)
                __hip_atomic_store(&arrive[w], (unsigned)(t + 1),
                                   __ATOMIC_RELEASE, __HIP_MEMORY_SCOPE_AGENT);
            if (tid < 128) {
                long guard = 0;
                while (__hip_atomic_load(&arrive[tid], __ATOMIC_ACQUIRE,
                                         __HIP_MEMORY_SCOPE_AGENT) < (unsigned)(t + 1)) {
                    __builtin_amdgcn_s_sleep(1);
                    if (++guard > (1L << 22)) break;   // anti-deadlock escape
                }
            }
            __syncthreads();
        }
    }
}

// ---------------- logits = seq @ Wd^T' + bd : 512 WGs x 64 rows
__global__ void k_logits(const bf16_t* __restrict__ seq, const bf16_t* __restrict__ WdT,
                         const float* __restrict__ bd, float* __restrict__ out) {
    const int m0 = blockIdx.x * 64;
    const int lane = threadIdx.x & 63, wave = threadIdx.x >> 6;
    const int r16 = lane & 15, grp = lane >> 4;
    f32x4 acc[8];
#pragma unroll
    for (int n = 0; n < 8; ++n) acc[n] = (f32x4){0.f, 0.f, 0.f, 0.f};
    const bf16_t* ap = seq + (m0 + 16 * wave + r16) * kH + 8 * grp;
    const bf16_t* bp = WdT + r16 * kH + 8 * grp;
    for (int ks = 0; ks < 32; ++ks) {
        const int k0 = 32 * ks;
        bf16x8 a = *(const bf16x8*)(ap + k0);
#pragma unroll
        for (int nt = 0; nt < 8; ++nt) {
            bf16x8 b = *(const bf16x8*)(bp + nt * 16 * kH + k0);
            acc[nt] = __builtin_amdgcn_mfma_f32_16x16x32_bf16(a, b, acc[nt], 0, 0, 0);
        }
    }
#pragma unroll
    for (int nt = 0; nt < 8; ++nt) {
        const int v = 16 * nt + r16;
        const float bias = bd[v];
#pragma unroll
        for (int q = 0; q < 4; ++q) {
            const int m = m0 + 16 * wave + 4 * grp + q;
            out[m * kV + v] = acc[nt][q] + bias;
        }
    }
}

extern "C" void kernel_launch(void* const* d_in, const int* in_sizes, int n_in,
                              void* d_out, int out_size, void* d_ws, size_t ws_size,
                              hipStream_t stream) {
    const int*   tokens = (const int*)d_in[0];
    const float* emb    = (const float*)d_in[1];
    const float* Wx     = (const float*)d_in[2];
    const float* Uh     = (const float*)d_in[3];
    const float* b_in   = (const float*)d_in[4];
    const float* b_rec  = (const float*)d_in[5];
    const float* Wd     = (const float*)d_in[6];
    const float* bd     = (const float*)d_in[7];
    float* out = (float*)d_out;

    char* ws = (char*)d_ws;
    bf16_t*   seq    = (bf16_t*)ws;                    // 64*512*1024*2 = 67,108,864 B
    float*    P      = (float*)(ws + 67108864);        // 128*3072*4   =  1,572,864 B
    bf16_t*   WdT    = (bf16_t*)(ws + 68681728);       // 128*1024*2   =    262,144 B
    bf16_t*   hbuf   = (bf16_t*)(ws + 68943872);       // 2*64*1024*2  =    262,144 B
    unsigned* arrive = (unsigned*)(ws + 69206016);     // 128*4 B (memset per launch)

    k_prep_P<<<dim3(12, 4), 256, 0, stream>>>(emb, Wx, b_in, b_rec, P);
    k_prep_WdT<<<512, 256, 0, stream>>>(Wd, WdT);
    hipMemsetAsync(arrive, 0, 4096, stream);
    k_scan<<<128, 256, 0, stream>>>(tokens, Uh, P, b_rec, hbuf, seq, arrive);
    k_logits<<<512, 256, 0, stream>>>(seq, WdT, bd, out);
}

// Round 3
// 7333.763 us; speedup vs baseline: 1.3150x; 1.3128x over previous
//
#include <hip/hip_runtime.h>
#include <stdint.h>

constexpr int kV = 128, kE = 100, kH = 1024, kB = 64, kT = 512, kH3 = 3072;

typedef __bf16 bf16_t;
typedef __bf16 bf16x8 __attribute__((ext_vector_type(8)));
typedef float f32x4 __attribute__((ext_vector_type(4)));

// ---------------- P = emb @ Wx + b_in (+ b_rec for z,r gates) : [128][3072] f32
__global__ void k_prep_P(const float* __restrict__ emb, const float* __restrict__ Wx,
                         const float* __restrict__ b_in, const float* __restrict__ b_rec,
                         float* __restrict__ P) {
    const int n = blockIdx.x * 256 + threadIdx.x;   // 12 blocks.x * 256 = 3072
    const int v0 = blockIdx.y * 32;                 // 4 blocks.y
    float wcol[kE];
#pragma unroll
    for (int e = 0; e < kE; ++e) wcol[e] = Wx[e * kH3 + n];
    const float bias = b_in[n] + (n < 2 * kH ? b_rec[n] : 0.f);
    for (int vi = 0; vi < 32; ++vi) {
        const int v = v0 + vi;
        float acc = bias;
#pragma unroll
        for (int e = 0; e < kE; ++e) acc += emb[v * kE + e] * wcol[e];
        P[v * kH3 + n] = acc;
    }
}

// ---------------- WdT = bf16(Wd^T) : [128][1024]
__global__ void k_prep_WdT(const float* __restrict__ Wd, bf16_t* __restrict__ WdT) {
    const int i = blockIdx.x * 256 + threadIdx.x;   // 512 blocks -> 131072
    const int v = i & 127, k = i >> 7;
    WdT[v * kH + k] = (bf16_t)Wd[k * kV + v];
}

// ---------------- tokT[t][b] = tokens[b][t] : coalesced per-step token column
__global__ void k_prep_tokT(const int* __restrict__ tokens, int* __restrict__ tokT) {
    const int i = blockIdx.x * 256 + threadIdx.x;   // 128 blocks -> 32768
    const int b = i & 63, t = i >> 6;
    tokT[i] = tokens[b * kT + t];
}

// ---------------- persistent GRU scan: 128 WGs x 256 thr, WG w owns H-cols [8w,8w+8)
__launch_bounds__(256, 1)
__global__ void k_scan(const int* __restrict__ tokT, const float* __restrict__ Uh,
                       const float* __restrict__ Pg, const float* __restrict__ b_rec,
                       bf16_t* __restrict__ hbuf, bf16_t* __restrict__ seq,
                       unsigned* __restrict__ arrive) {
    // 40 rows (32 used) to push LDS > 80KB -> exactly 1 WG/CU -> 128 CUs busy
    __shared__ __align__(16) bf16_t UhT[40][1032];
    __shared__ float Pl[kV][24];
    const int w = blockIdx.x;
    const int tid = threadIdx.x;
    const int lane = tid & 63, wave = tid >> 6;
    const int r16 = lane & 15, grp = lane >> 4;

    // zero the 32 used UhT rows (cols 24..31 stay zero = N-pad)
    for (int i = tid; i < 32 * 1032; i += 256) ((bf16_t*)UhT)[i] = (bf16_t)0.f;
    __syncthreads();
    // stage Uh slice, transposed, bf16:  UhT[n][k] = Uh[k][col(n)]
    for (int idx = tid; idx < 24 * 1024; idx += 256) {
        const int n = idx % 24, k = idx / 24;
        const int c = (n < 8) ? (8 * w + n) : (n < 16) ? (kH + 8 * w + n - 8) : (2 * kH + 8 * w + n - 16);
        UhT[n][k] = (bf16_t)Uh[k * kH3 + c];
    }
    // stage P gather table for this WG's 24 columns
    for (int idx = tid; idx < kV * 24; idx += 256) {
        const int v = idx / 24, n = idx % 24;
        const int c = (n < 8) ? (8 * w + n) : (n < 16) ? (kH + 8 * w + n - 8) : (2 * kH + 8 * w + n - 16);
        Pl[v][n] = Pg[v * kH3 + c];
    }
    __syncthreads();

    const bool act = (r16 < 8);
    const int jj = r16;
    const int jcol = 8 * w + jj;
    const float brh = act ? b_rec[2 * kH + jcol] : 0.f;   // hh-gate bias (scaled by r, not foldable)
    float hreg[4] = {0.f, 0.f, 0.f, 0.f};                 // this lane's h[b][jcol] state, f32

    int4 tok4 = *(const int4*)(tokT + 0 * kB + 16 * wave + 4 * grp);

    for (int t = 0; t < kT; ++t) {
        const int cur = t & 1;
        const bf16_t* __restrict__ hprev = hbuf + (cur ^ 1) * (kB * kH);
        bf16_t* __restrict__ hnext = hbuf + cur * (kB * kH);

        f32x4 acc0 = {0.f, 0.f, 0.f, 0.f};   // N-tile 0: cols n=0..15  (z: n<8, r: 8..15)
        f32x4 acc1 = {0.f, 0.f, 0.f, 0.f};   // N-tile 1: cols n=16..31 (hh: 16..23)
        if (t > 0) {
            // one L1+L2 invalidate per step; then plain cached wide loads see
            // the MALL-fresh h written by other XCDs' agent-scope stores.
            __builtin_amdgcn_fence(__ATOMIC_ACQUIRE, "agent");
            const bf16_t* aptr = hprev + (16 * wave + r16) * kH + 8 * grp;
            bf16x8 av[32];
#pragma unroll
            for (int ks = 0; ks < 32; ++ks)
                av[ks] = *(const bf16x8*)(aptr + 32 * ks);
#pragma unroll
            for (int ks = 0; ks < 32; ++ks) {
                const int kk = 32 * ks + 8 * grp;
                bf16x8 b0 = *(const bf16x8*)&UhT[r16][kk];
                bf16x8 b1 = *(const bf16x8*)&UhT[16 + r16][kk];
                acc0 = __builtin_amdgcn_mfma_f32_16x16x32_bf16(av[ks], b0, acc0, 0, 0, 0);
                acc1 = __builtin_amdgcn_mfma_f32_16x16x32_bf16(av[ks], b1, acc1, 0, 0, 0);
            }
        }

        // bring r-gate pre-activations (cols 8..15) to the z-lanes (cols 0..7)
        float racc[4];
#pragma unroll
        for (int q = 0; q < 4; ++q) racc[q] = __shfl_xor(acc0[q], 8, 64);

        bf16_t hv[4];
        if (act) {
#pragma unroll
            for (int q = 0; q < 4; ++q) {
                const int b = 16 * wave + 4 * grp + q;
                const int tok = (q == 0) ? tok4.x : (q == 1) ? tok4.y : (q == 2) ? tok4.z : tok4.w;
                const float xz = Pl[tok][jj];
                const float xr = Pl[tok][8 + jj];
                const float xh = Pl[tok][16 + jj];
                const float z = 1.f / (1.f + __expf(-(xz + acc0[q])));
                const float r = 1.f / (1.f + __expf(-(xr + racc[q])));
                float hh = xh + r * (acc1[q] + brh);
                hh = hh > 0.f ? hh : 0.f;
                const float hnew = z * hreg[q] + (1.f - z) * hh;
                hreg[q] = hnew;
                union { bf16_t h; unsigned short u; } cv; cv.h = (bf16_t)hnew;
                hv[q] = cv.h;
                __hip_atomic_store((unsigned short*)(hnext + b * kH + jcol), cv.u,
                                   __ATOMIC_RELAXED, __HIP_MEMORY_SCOPE_AGENT);
            }
        }

        if (t < kT - 1) {
            // prefetch next step's tokens (read-only data, safe across fence)
            const int4 tok4n = *(const int4*)(tokT + (t + 1) * kB + 16 * wave + 4 * grp);
            // __syncthreads drains vmcnt(0) for all waves (h stores complete at MALL)
            __syncthreads();
            if (tid == 0)
                __hip_atomic_store(&arrive[w], (unsigned)(t + 1),
                                   __ATOMIC_RELEASE, __HIP_MEMORY_SCOPE_AGENT);
            if (tid < 64) {
                long guard = 0;
                for (;;) {
                    const unsigned a0 = __hip_atomic_load(&arrive[tid], __ATOMIC_RELAXED,
                                                          __HIP_MEMORY_SCOPE_AGENT);
                    const unsigned a1 = __hip_atomic_load(&arrive[tid + 64], __ATOMIC_RELAXED,
                                                          __HIP_MEMORY_SCOPE_AGENT);
                    if (a0 > (unsigned)t && a1 > (unsigned)t) break;
                    __builtin_amdgcn_s_sleep(2);
                    if (++guard > (1L << 22)) break;   // anti-deadlock escape
                }
            }
            __syncthreads();
            // seq store AFTER the barrier: overlaps next step's A-load phase
            if (act) {
#pragma unroll
                for (int q = 0; q < 4; ++q) {
                    const int b = 16 * wave + 4 * grp + q;
                    seq[(b * kT + t) * kH + jcol] = hv[q];
                }
            }
            tok4 = tok4n;
        } else if (act) {
#pragma unroll
            for (int q = 0; q < 4; ++q) {
                const int b = 16 * wave + 4 * grp + q;
                seq[(b * kT + t) * kH + jcol] = hv[q];
            }
        }
    }
}

// ---------------- logits = seq @ Wd^T' + bd : 512 WGs x 64 rows
__global__ void k_logits(const bf16_t* __restrict__ seq, const bf16_t* __restrict__ WdT,
                         const float* __restrict__ bd, float* __restrict__ out) {
    const int m0 = blockIdx.x * 64;
    const int lane = threadIdx.x & 63, wave = threadIdx.x >> 6;
    const int r16 = lane & 15, grp = lane >> 4;
    f32x4 acc[8];
#pragma unroll
    for (int n = 0; n < 8; ++n) acc[n] = (f32x4){0.f, 0.f, 0.f, 0.f};
    const bf16_t* ap = seq + (m0 + 16 * wave + r16) * kH + 8 * grp;
    const bf16_t* bp = WdT + r16 * kH + 8 * grp;
    for (int ks = 0; ks < 32; ++ks) {
        const int k0 = 32 * ks;
        bf16x8 a = *(const bf16x8*)(ap + k0);
#pragma unroll
        for (int nt = 0; nt < 8; ++nt) {
            bf16x8 b = *(const bf16x8*)(bp + nt * 16 * kH + k0);
            acc[nt] = __builtin_amdgcn_mfma_f32_16x16x32_bf16(a, b, acc[nt], 0, 0, 0);
        }
    }
#pragma unroll
    for (int nt = 0; nt < 8; ++nt) {
        const int v = 16 * nt + r16;
        const float bias = bd[v];
#pragma unroll
        for (int q = 0; q < 4; ++q) {
            const int m = m0 + 16 * wave + 4 * grp + q;
            out[m * kV + v] = acc[nt][q] + bias;
        }
    }
}

extern "C" void kernel_launch(void* const* d_in, const int* in_sizes, int n_in,
                              void* d_out, int out_size, void* d_ws, size_t ws_size,
                              hipStream_t stream) {
    const int*   tokens = (const int*)d_in[0];
    const float* emb    = (const float*)d_in[1];
    const float* Wx     = (const float*)d_in[2];
    const float* Uh     = (const float*)d_in[3];
    const float* b_in   = (const float*)d_in[4];
    const float* b_rec  = (const float*)d_in[5];
    const float* Wd     = (const float*)d_in[6];
    const float* bd     = (const float*)d_in[7];
    float* out = (float*)d_out;

    char* ws = (char*)d_ws;
    bf16_t*   seq    = (bf16_t*)ws;                    // 64*512*1024*2 = 67,108,864 B
    float*    P      = (float*)(ws + 67108864);        // 128*3072*4   =  1,572,864 B
    bf16_t*   WdT    = (bf16_t*)(ws + 68681728);       // 128*1024*2   =    262,144 B
    bf16_t*   hbuf   = (bf16_t*)(ws + 68943872);       // 2*64*1024*2  =    262,144 B
    unsigned* arrive = (unsigned*)(ws + 69206016);     //  4,096 B (memset per launch)
    int*      tokT   = (int*)(ws + 69210112);          // 32768*4      =    131,072 B

    k_prep_P<<<dim3(12, 4), 256, 0, stream>>>(emb, Wx, b_in, b_rec, P);
    k_prep_WdT<<<512, 256, 0, stream>>>(Wd, WdT);
    k_prep_tokT<<<128, 256, 0, stream>>>(tokens, tokT);
    hipMemsetAsync(arrive, 0, 4096, stream);
    k_scan<<<128, 256, 0, stream>>>(tokT, Uh, P, b_rec, hbuf, seq, arrive);
    k_logits<<<512, 256, 0, stream>>>(seq, WdT, bd, out);
}

// Round 5
// 5066.488 us; speedup vs baseline: 1.9034x; 1.4475x over previous
//
#include <hip/hip_runtime.h>
#include <stdint.h>

constexpr int kV = 128, kE = 100, kH = 1024, kB = 64, kT = 512, kH3 = 3072;

typedef __bf16 bf16_t;
typedef __bf16 bf16x8 __attribute__((ext_vector_type(8)));
typedef float f32x4 __attribute__((ext_vector_type(4)));

// ---------------- P = emb @ Wx + b_in (+ b_rec for z,r gates) : [128][3072] f32
__global__ void k_prep_P(const float* __restrict__ emb, const float* __restrict__ Wx,
                         const float* __restrict__ b_in, const float* __restrict__ b_rec,
                         float* __restrict__ P) {
    const int n = blockIdx.x * 256 + threadIdx.x;   // 12 blocks.x * 256 = 3072
    const int v0 = blockIdx.y * 32;                 // 4 blocks.y
    float wcol[kE];
#pragma unroll
    for (int e = 0; e < kE; ++e) wcol[e] = Wx[e * kH3 + n];
    const float bias = b_in[n] + (n < 2 * kH ? b_rec[n] : 0.f);
    for (int vi = 0; vi < 32; ++vi) {
        const int v = v0 + vi;
        float acc = bias;
#pragma unroll
        for (int e = 0; e < kE; ++e) acc += emb[v * kE + e] * wcol[e];
        P[v * kH3 + n] = acc;
    }
}

// ---------------- WdT = bf16(Wd^T) : [128][1024]
__global__ void k_prep_WdT(const float* __restrict__ Wd, bf16_t* __restrict__ WdT) {
    const int i = blockIdx.x * 256 + threadIdx.x;   // 512 blocks -> 131072
    const int v = i & 127, k = i >> 7;
    WdT[v * kH + k] = (bf16_t)Wd[k * kV + v];
}

// ---------------- persistent GRU scan:
// 256 WGs x 256 thr, logical group g = blockIdx>>5 owns batch rows [8g,8g+8);
// slot = blockIdx&31 owns h-cols [32s,32s+32). Wave w holds ALL 96 gate-cols of
// Uh for K-slice [256w,256w+256) in VGPRs; partial C reduced via LDS. All
// cross-WG data via relaxed AGENT atomics (known-working); flag = release store.
__launch_bounds__(256, 1)
__global__ void k_scan(const int* __restrict__ tokens, const float* __restrict__ Uh,
                       const float* __restrict__ Pg, const float* __restrict__ b_rec,
                       bf16_t* __restrict__ hbuf, bf16_t* __restrict__ seq,
                       unsigned* __restrict__ flags) {
    __shared__ float Pl[kV][104];       // [v][0:32)=z,[32:64)=r,[64:96)=hh (pads->LDS>80KB)
    __shared__ float part[4][24][100];  // [wave][row(8 used)][col 0:96) partial pre-acts
    const int tid = threadIdx.x;
    const int g = blockIdx.x >> 5, slot = blockIdx.x & 31;
    const int c0 = slot * 32;
    const int lane = tid & 63, wave = tid >> 6;
    const int r16 = lane & 15, grp = lane >> 4;

    // stage P gather table for this WG's 96 gate columns (b_in/b_rec(z,r) folded)
    for (int idx = tid; idx < kV * 96; idx += 256) {
        const int v = idx / 96, gi = idx % 96;
        const int col = (gi >> 5) * kH + c0 + (gi & 31);
        Pl[v][gi] = Pg[v * kH3 + col];
    }
    // B-fragments: all 6 output tiles x 8 K-steps for this wave's K-slice -> 192 VGPRs
    bf16x8 bf[6][8];
#pragma unroll
    for (int tile = 0; tile < 6; ++tile) {
        const int col = (tile >> 1) * kH + c0 + (tile & 1) * 16 + r16;
#pragma unroll
        for (int ks = 0; ks < 8; ++ks) {
#pragma unroll
            for (int j = 0; j < 8; ++j)
                bf[tile][ks][j] = (bf16_t)Uh[(wave * 256 + ks * 32 + grp * 8 + j) * kH3 + col];
        }
    }
    // wave 0 gate-lane constants: lane -> (row = lane>>3, 4 cols at c4 = (lane&7)*4)
    const int grow = lane >> 3, c4 = (lane & 7) * 4;
    float brh4[4], hreg[4] = {0.f, 0.f, 0.f, 0.f};
#pragma unroll
    for (int i = 0; i < 4; ++i) brh4[i] = b_rec[2 * kH + c0 + c4 + i];
    const int arow = r16 & 7;                      // A-frag local row (rows 8-15 dup)
    __syncthreads();

    for (int t = 0; t < kT; ++t) {
        // ---- wait: all 32 slots of this group published step t (4 waves x 8 flags)
        if (t > 0) {
            if (lane < 8) {
                const unsigned* fp = flags + g * 32 + wave * 8 + lane;
                long guard = 0;
                while (__hip_atomic_load(fp, __ATOMIC_RELAXED, __HIP_MEMORY_SCOPE_AGENT)
                       < (unsigned)t) {
                    __builtin_amdgcn_s_sleep(1);
                    if (++guard > (1L << 18)) break;   // anti-hang escape
                }
            }
        }
        __syncthreads();   // joins 4 waves' partial flag knowledge; LDS hazard fence

        // ---- partial matmul over this wave's K-slice
        f32x4 acc[6];
#pragma unroll
        for (int tile = 0; tile < 6; ++tile) acc[tile] = (f32x4){0.f, 0.f, 0.f, 0.f};
        if (t > 0) {
            const bf16_t* hprev = hbuf + (((t & 1) ^ 1) * kB + 8 * g) * kH;
            const unsigned long long* ap =
                (const unsigned long long*)(hprev + arow * kH + wave * 256 + grp * 8);
            bf16x8 av[8];
#pragma unroll
            for (int ks = 0; ks < 8; ++ks) {
                union { unsigned long long u[2]; bf16x8 v; } au;
                au.u[0] = __hip_atomic_load(ap + ks * 8, __ATOMIC_RELAXED,
                                            __HIP_MEMORY_SCOPE_AGENT);
                au.u[1] = __hip_atomic_load(ap + ks * 8 + 1, __ATOMIC_RELAXED,
                                            __HIP_MEMORY_SCOPE_AGENT);
                av[ks] = au.v;
            }
#pragma unroll
            for (int ks = 0; ks < 8; ++ks)
#pragma unroll
                for (int tile = 0; tile < 6; ++tile)
                    acc[tile] = __builtin_amdgcn_mfma_f32_16x16x32_bf16(av[ks], bf[tile][ks],
                                                                        acc[tile], 0, 0, 0);
            if (grp < 2) {      // rows 0-7 real; write partial pre-acts
#pragma unroll
                for (int tile = 0; tile < 6; ++tile)
#pragma unroll
                    for (int q = 0; q < 4; ++q)
                        part[wave][grp * 4 + q][tile * 16 + r16] = acc[tile][q];
            }
        }
        __syncthreads();

        // ---- wave 0: reduce partials, gates, state update, h/seq stores, publish
        if (wave == 0) {
            const int tok = tokens[(8 * g + grow) * kT + t];
            f32x4 rz = {0.f, 0.f, 0.f, 0.f}, rr = rz, rh = rz;
            if (t > 0) {
#pragma unroll
                for (int w2 = 0; w2 < 4; ++w2) {
                    rz += *(const f32x4*)&part[w2][grow][c4];
                    rr += *(const f32x4*)&part[w2][grow][32 + c4];
                    rh += *(const f32x4*)&part[w2][grow][64 + c4];
                }
            }
            union { bf16_t h[4]; unsigned long long u; } hp;
#pragma unroll
            for (int i = 0; i < 4; ++i) {
                const float z = 1.f / (1.f + __expf(-(Pl[tok][c4 + i] + rz[i])));
                const float r = 1.f / (1.f + __expf(-(Pl[tok][32 + c4 + i] + rr[i])));
                float hh = Pl[tok][64 + c4 + i] + r * (rh[i] + brh4[i]);
                hh = hh > 0.f ? hh : 0.f;
                const float hnew = z * hreg[i] + (1.f - z) * hh;
                hreg[i] = hnew;
                hp.h[i] = (bf16_t)hnew;
            }
            if (t < kT - 1)
                __hip_atomic_store((unsigned long long*)(hbuf + (((t & 1) * kB) + 8 * g + grow) * kH
                                                         + c0 + c4),
                                   hp.u, __ATOMIC_RELAXED, __HIP_MEMORY_SCOPE_AGENT);
            *(unsigned long long*)(seq + ((8 * g + grow) * kT + t) * kH + c0 + c4) = hp.u;
            if (t < kT - 1 && lane == 0)
                __hip_atomic_store(&flags[g * 32 + slot], (unsigned)(t + 1),
                                   __ATOMIC_RELEASE, __HIP_MEMORY_SCOPE_AGENT);
        }
    }
}

// ---------------- logits = seq @ Wd^T' + bd : 512 WGs x 64 rows
__global__ void k_logits(const bf16_t* __restrict__ seq, const bf16_t* __restrict__ WdT,
                         const float* __restrict__ bd, float* __restrict__ out) {
    const int m0 = blockIdx.x * 64;
    const int lane = threadIdx.x & 63, wave = threadIdx.x >> 6;
    const int r16 = lane & 15, grp = lane >> 4;
    f32x4 acc[8];
#pragma unroll
    for (int n = 0; n < 8; ++n) acc[n] = (f32x4){0.f, 0.f, 0.f, 0.f};
    const bf16_t* ap = seq + (m0 + 16 * wave + r16) * kH + 8 * grp;
    const bf16_t* bp = WdT + r16 * kH + 8 * grp;
    for (int ks = 0; ks < 32; ++ks) {
        const int k0 = 32 * ks;
        bf16x8 a = *(const bf16x8*)(ap + k0);
#pragma unroll
        for (int nt = 0; nt < 8; ++nt) {
            bf16x8 b = *(const bf16x8*)(bp + nt * 16 * kH + k0);
            acc[nt] = __builtin_amdgcn_mfma_f32_16x16x32_bf16(a, b, acc[nt], 0, 0, 0);
        }
    }
#pragma unroll
    for (int nt = 0; nt < 8; ++nt) {
        const int v = 16 * nt + r16;
        const float bias = bd[v];
#pragma unroll
        for (int q = 0; q < 4; ++q) {
            const int m = m0 + 16 * wave + 4 * grp + q;
            out[m * kV + v] = acc[nt][q] + bias;
        }
    }
}

extern "C" void kernel_launch(void* const* d_in, const int* in_sizes, int n_in,
                              void* d_out, int out_size, void* d_ws, size_t ws_size,
                              hipStream_t stream) {
    const int*   tokens = (const int*)d_in[0];
    const float* emb    = (const float*)d_in[1];
    const float* Wx     = (const float*)d_in[2];
    const float* Uh     = (const float*)d_in[3];
    const float* b_in   = (const float*)d_in[4];
    const float* b_rec  = (const float*)d_in[5];
    const float* Wd     = (const float*)d_in[6];
    const float* bd     = (const float*)d_in[7];
    float* out = (float*)d_out;

    char* ws = (char*)d_ws;
    bf16_t*   seq   = (bf16_t*)ws;                    // 64*512*1024*2 = 67,108,864 B
    float*    P     = (float*)(ws + 67108864);        // 128*3072*4   =  1,572,864 B
    bf16_t*   WdT   = (bf16_t*)(ws + 68681728);       // 128*1024*2   =    262,144 B
    bf16_t*   hbuf  = (bf16_t*)(ws + 68943872);       // 2*64*1024*2  =    262,144 B
    unsigned* flags = (unsigned*)(ws + 69206016);     // 256*4 = 1024 B (memset/launch)

    k_prep_P<<<dim3(12, 4), 256, 0, stream>>>(emb, Wx, b_in, b_rec, P);
    k_prep_WdT<<<512, 256, 0, stream>>>(Wd, WdT);
    hipMemsetAsync(flags, 0, 1024, stream);
    k_scan<<<256, 256, 0, stream>>>(tokens, Uh, P, b_rec, hbuf, seq, flags);
    k_logits<<<512, 256, 0, stream>>>(seq, WdT, bd, out);
}